// Round 16
// baseline (189.734 us; speedup 1.0000x reference)
//
#include <hip/hip_runtime.h>

#define NB 1024
#define NR 100

typedef _Float16 half_t;
typedef half_t f16x8 __attribute__((ext_vector_type(8)));
typedef float f32x4 __attribute__((ext_vector_type(4)));
typedef float f32x2 __attribute__((ext_vector_type(2)));

__device__ __forceinline__ int kmap2(int g, int j) {
    return g*4 + (j & 3) + ((j >> 2) << 4);
}

__device__ __forceinline__ f32x2 pkfma(f32x2 a, float s, f32x2 c) {
    return __builtin_elementwise_fma(a, (f32x2){s, s}, c);
}

// async global->LDS, 16B per lane; LDS dest = base + lane*16 (HW behavior)
#define GLDS(gsrc, ldst) \
    __builtin_amdgcn_global_load_lds( \
        (const __attribute__((address_space(1))) void*)(gsrc), \
        (__attribute__((address_space(3))) void*)(ldst), 16, 0, 0)

// ---------------------------------------------------------------------------
// conv12ws: blocks [0,1700) = wsplit (FRONT-loaded: short memory-bound blocks
// drain first, overlapping conv12's ramp); blocks [1700, 5796) = fused
// conv1->conv2 per image quadrant. Independent work, disjoint outputs.
// ---------------------------------------------------------------------------
#define EOFF 2268
#define IO   1568
#define NWSP 1700
__global__ __launch_bounds__(256, 5) void conv12ws_k(const float* __restrict__ x,
        const float* __restrict__ c1w, const float* __restrict__ b1c,
        const float* __restrict__ c2w, const float* __restrict__ b2c,
        float* __restrict__ out,
        const float* __restrict__ w1, const float* __restrict__ w2,
        const float* __restrict__ w3, const float* __restrict__ w4,
        half_t* __restrict__ f1h, half_t* __restrict__ f1l,
        half_t* __restrict__ f2h, half_t* __restrict__ f2l,
        half_t* __restrict__ f3h, half_t* __restrict__ f3l,
        half_t* __restrict__ f4h, half_t* __restrict__ f4l) {
    __shared__ float pool[7510];
    const int bid0 = blockIdx.x;
    const int tid = threadIdx.x;

    if (bid0 < NWSP) {
        // ---------------- wsplit ----------------
        const int cx = bid0 % 17, r = bid0 / 17;
        float* lds = pool;
        int K, N, KC, NF, kc;
        const float* src;
        half_t *dh, *dl;
        if (cx < 7)       { K=200; N=140; KC=7; NF=9; kc=cx;    src=w1; dh=f1h; dl=f1l; }
        else if (cx < 12) { K=140; N=84;  KC=5; NF=6; kc=cx-7;  src=w2; dh=f2h; dl=f2l; }
        else if (cx < 15) { K=84;  N=42;  KC=3; NF=3; kc=cx-12; src=w3; dh=f3h; dl=f3l; }
        else              { K=42;  N=4;   KC=2; NF=1; kc=cx-15; src=w4; dh=f4h; dl=f4l; }
        const float* sb = src + (size_t)r * K * N;
        for (int i = tid; i < 32*N; i += 256) {
            const int kk = i / N, n = i - kk*N;
            const int kg = kc*32 + kk;
            lds[kk*N + n] = (kg < K) ? sb[(size_t)kg*N + n] : 0.f;
        }
        __syncthreads();
        const size_t base = ((size_t)r*KC + kc)*NF*512;
        for (int e = tid; e < NF*512; e += 256) {
            const int nf = e >> 9, rem = e & 511;
            const int l = rem >> 3, j = rem & 7;
            const int g = l >> 4, c = l & 15;
            const int kl = kmap2(g, j);
            const int n = nf*16 + c;
            const float v = (n < N) ? lds[kl*N + n] : 0.f;
            const half_t hi = (half_t)v;
            const half_t lo = (half_t)(v - (float)hi);
            dh[base + (size_t)nf*512 + rem] = hi;
            dl[base + (size_t)nf*512 + rem] = lo;
        }
        return;
    }

    // ---------------- conv12 ----------------
    const int bid = bid0 - NWSP;
    float* img = pool;
    float* c1p = pool + 3136;
    const int b  = bid >> 2;
    const int qy = (bid >> 1) & 1, qx = bid & 1;
    const int R0 = 44*qy - 1, C0 = 44*qx - 1;
    const float* xb = x + (size_t)b * 9604;

    for (int i = tid; i < 3136; i += 256) {
        const int rr = i / 56, cc = i - rr*56;
        const int gr = R0 + rr, gc = C0 + cc;
        float v = 0.f;
        if (gr >= 0 && gr < 98 && gc >= 0 && gc < 98) v = xb[gr*98 + gc];
        img[((cc & 1) ? IO : 0) + rr*28 + (cc >> 1)] = v;
    }
    __syncthreads();

    // conv1
    for (int pos = tid; pos < 729; pos += 256) {
        const int py = pos / 27, px = pos - py*27;
        float p[4][4];
        #pragma unroll
        for (int u = 0; u < 4; ++u) {
            const int ro = (2*py + u)*28;
            p[u][0] = img[ro + px];
            p[u][2] = img[ro + px + 1];
            p[u][1] = img[IO + ro + px];
            p[u][3] = img[IO + ro + px + 1];
        }
        f32x2 a2[3][4];
        #pragma unroll
        for (int g = 0; g < 3; ++g) {
            const f32x2 bv = {b1c[g*2], b1c[g*2+1]};
            a2[g][0] = a2[g][1] = a2[g][2] = a2[g][3] = bv;
        }
        #pragma unroll
        for (int ky = 0; ky < 3; ++ky)
            #pragma unroll
            for (int kx = 0; kx < 3; ++kx) {
                const int k = ky*3 + kx;
                const float q0 = p[ky  ][kx], q1 = p[ky  ][kx+1];
                const float q2 = p[ky+1][kx], q3 = p[ky+1][kx+1];
                #pragma unroll
                for (int g = 0; g < 3; ++g) {
                    const f32x2 wv = {c1w[(g*2)*9 + k], c1w[(g*2+1)*9 + k]};
                    a2[g][0] = pkfma(wv, q0, a2[g][0]);
                    a2[g][1] = pkfma(wv, q1, a2[g][1]);
                    a2[g][2] = pkfma(wv, q2, a2[g][2]);
                    a2[g][3] = pkfma(wv, q3, a2[g][3]);
                }
            }
        const int par = px & 1, pi = px >> 1;
        #pragma unroll
        for (int g = 0; g < 3; ++g) {
            const float m0 = fmaxf(fmaxf(a2[g][0].x, a2[g][1].x),
                                   fmaxf(a2[g][2].x, a2[g][3].x));
            const float m1 = fmaxf(fmaxf(a2[g][0].y, a2[g][1].y),
                                   fmaxf(a2[g][2].y, a2[g][3].y));
            const int e0 = par ? (EOFF + ((2*g    )*27 + py)*13 + pi)
                               : (((2*g    )*27 + py)*14 + pi);
            const int e1 = par ? (EOFF + ((2*g + 1)*27 + py)*13 + pi)
                               : (((2*g + 1)*27 + py)*14 + pi);
            c1p[e0] = fmaxf(m0, 0.f);
            c1p[e1] = fmaxf(m1, 0.f);
        }
    }
    __syncthreads();

    // conv2: ic-split, 4 oc per active lane
    const int wv_ = tid >> 6;
    const int ich = __builtin_amdgcn_readfirstlane(tid >> 7);
    const int unit = ((wv_ & 1) << 6) | (tid & 63);
    const bool act = unit < 121;
    const int py = act ? unit / 11 : 0;
    const int px = act ? unit - py*11 : 0;
    const int y0 = 2*py;

    f32x2 acc[2][2][2] = {};
    if (act) {
        #pragma unroll
        for (int ic3 = 0; ic3 < 3; ++ic3) {
            const int ic = ich*3 + ic3;
            const float* pe0 = c1p + (ic*27 + y0)*14 + px;
            const float* po0 = c1p + EOFF + (ic*27 + y0)*13 + px;
            #pragma unroll
            for (int u = 0; u < 7; ++u) {
                const float* pe = pe0 + u*14;
                const float* po = po0 + u*13;
                float pr[7];
                pr[0] = pe[0]; pr[2] = pe[1]; pr[4] = pe[2]; pr[6] = pe[3];
                pr[1] = po[0]; pr[3] = po[1]; pr[5] = po[2];
                #pragma unroll
                for (int dy = 0; dy < 2; ++dy) {
                    const int ky = u - dy;
                    if (ky < 0 || ky > 5) continue;
                    #pragma unroll
                    for (int kx = 0; kx < 6; ++kx) {
                        const int idx = ic*36 + ky*6 + kx;
                        const f32x2 w0 = {c2w[idx],       c2w[216 + idx]};
                        const f32x2 w1 = {c2w[432 + idx], c2w[648 + idx]};
                        acc[0][dy][0] = pkfma(w0, pr[0+kx], acc[0][dy][0]);
                        acc[0][dy][1] = pkfma(w0, pr[1+kx], acc[0][dy][1]);
                        acc[1][dy][0] = pkfma(w1, pr[0+kx], acc[1][dy][0]);
                        acc[1][dy][1] = pkfma(w1, pr[1+kx], acc[1][dy][1]);
                    }
                }
            }
        }
    }
    float* pbuf = img;
    if (act && ich == 1) {
        #pragma unroll
        for (int p = 0; p < 2; ++p)
            #pragma unroll
            for (int dy = 0; dy < 2; ++dy)
                #pragma unroll
                for (int dx = 0; dx < 2; ++dx) {
                    const int j = ((p*2 + dy)*2 + dx)*2;
                    pbuf[(j    )*128 + unit] = acc[p][dy][dx].x;
                    pbuf[(j + 1)*128 + unit] = acc[p][dy][dx].y;
                }
    }
    __syncthreads();
    if (act && ich == 0) {
        #pragma unroll
        for (int p = 0; p < 2; ++p)
            #pragma unroll
            for (int dy = 0; dy < 2; ++dy)
                #pragma unroll
                for (int dx = 0; dx < 2; ++dx) {
                    const int j = ((p*2 + dy)*2 + dx)*2;
                    acc[p][dy][dx].x += pbuf[(j    )*128 + unit];
                    acc[p][dy][dx].y += pbuf[(j + 1)*128 + unit];
                }
        const int PY = qy*11 + py, PX = qx*11 + px;
        #pragma unroll
        for (int p = 0; p < 2; ++p) {
            const float m0 = fmaxf(fmaxf(acc[p][0][0].x, acc[p][0][1].x),
                                   fmaxf(acc[p][1][0].x, acc[p][1][1].x)) + b2c[p*2];
            const float m1 = fmaxf(fmaxf(acc[p][0][0].y, acc[p][0][1].y),
                                   fmaxf(acc[p][1][0].y, acc[p][1][1].y)) + b2c[p*2+1];
            out[(((size_t)b*4 + p*2    )*22 + PY)*22 + PX] = fmaxf(m0, 0.f);
            out[(((size_t)b*4 + p*2 + 1)*22 + PY)*22 + PX] = fmaxf(m1, 0.f);
        }
    }
}

// ---------------------------------------------------------------------------
// conv3: in[B,4,22,22] -> out[B,200]
// ---------------------------------------------------------------------------
__global__ __launch_bounds__(256) void conv3_k(const float* __restrict__ in,
        const float* __restrict__ w, const float* __restrict__ bias,
        float* __restrict__ out) {
    __shared__ float sm[1936];
    const int b = blockIdx.x;
    const int tid = threadIdx.x;
    const float* src = in + (size_t)b * 1936;
    for (int i = tid; i < 484; i += 256)
        ((float4*)sm)[i] = ((const float4*)src)[i];
    __syncthreads();
    if (tid < 200) {
        const int c = tid / 100;
        const int rem = tid % 100;
        const int py = rem / 10, px = rem % 10;
        const int y0 = 2*py, x0 = 2*px;
        float a0, a1, a2, a3;
        a0 = a1 = a2 = a3 = bias[c];
        #pragma unroll
        for (int ic = 0; ic < 4; ++ic) {
            float p[4][4];
            const float* base = sm + ic*484 + y0*22 + x0;
            #pragma unroll
            for (int u = 0; u < 4; ++u)
                #pragma unroll
                for (int v = 0; v < 4; ++v)
                    p[u][v] = base[u*22 + v];
            #pragma unroll
            for (int ky = 0; ky < 3; ++ky) {
                #pragma unroll
                for (int kx = 0; kx < 3; ++kx) {
                    const float wv = w[(c*4 + ic)*9 + ky*3 + kx];
                    a0 = fmaf(wv, p[ky  ][kx  ], a0);
                    a1 = fmaf(wv, p[ky  ][kx+1], a1);
                    a2 = fmaf(wv, p[ky+1][kx  ], a2);
                    a3 = fmaf(wv, p[ky+1][kx+1], a3);
                }
            }
        }
        float m = fmaxf(fmaxf(a0, a1), fmaxf(a2, a3));
        out[(size_t)b*200 + tid] = fmaxf(m, 0.f);
    }
}

// ---------------------------------------------------------------------------
// gemm body (fc1 / fc2). G0OUT: packed f16 hi/lo fragment planes + pad fill.
// ---------------------------------------------------------------------------
template<bool G0OUT>
__device__ __forceinline__ void gemm_body(float* pool, int bx, int by,
        const float* __restrict__ A, int lda,
        const float* __restrict__ W, const float* __restrict__ bias,
        float* __restrict__ C, int ldc,
        int M, int N, int K,
        half_t* __restrict__ g0h, half_t* __restrict__ g0l) {
    float (*As)[132] = (float(*)[132])pool;
    float* Ws = pool + 32*132;
    const int m0 = by * 128;
    const int n0 = bx * 64;
    const int tid = threadIdx.x;
    const int ti = tid >> 4, tj = tid & 15;
    float acc[8][4];
    #pragma unroll
    for (int i = 0; i < 8; ++i)
        #pragma unroll
        for (int j = 0; j < 4; ++j) acc[i][j] = 0.f;

    for (int k0 = 0; k0 < K; k0 += 32) {
        #pragma unroll
        for (int i = 0; i < 4; ++i) {
            const int f = tid + i*256;
            const int m = f >> 3, kg = f & 7;
            const int kk = kg*4;
            float4 v = make_float4(0.f, 0.f, 0.f, 0.f);
            if (k0 + kk < K)
                v = *(const float4*)(A + (long)(m0 + m)*lda + k0 + kk);
            As[kk+0][m] = v.x;
            As[kk+1][m] = v.y;
            As[kk+2][m] = v.z;
            As[kk+3][m] = v.w;
        }
        #pragma unroll
        for (int i = 0; i < 2; ++i) {
            const int f = tid + i*256;
            const int kk = f >> 4, cg = f & 15;
            const int n = n0 + cg*4;
            float4 v = make_float4(0.f, 0.f, 0.f, 0.f);
            if (k0 + kk < K) {
                const float* wp = W + (long)(k0 + kk)*N;
                if (n + 3 < N) v = *(const float4*)(wp + n);
                else {
                    if (n+0 < N) v.x = wp[n+0];
                    if (n+1 < N) v.y = wp[n+1];
                    if (n+2 < N) v.z = wp[n+2];
                }
            }
            *(float4*)&Ws[kk*64 + cg*4] = v;
        }
        __syncthreads();
        #pragma unroll
        for (int kk = 0; kk < 32; ++kk) {
            float a[8], wv[4];
            *(float4*)&a[0] = *(const float4*)&As[kk][ti*8];
            *(float4*)&a[4] = *(const float4*)&As[kk][ti*8 + 4];
            *(float4*)&wv[0] = *(const float4*)&Ws[kk*64 + tj*4];
            #pragma unroll
            for (int i = 0; i < 8; ++i)
                #pragma unroll
                for (int j = 0; j < 4; ++j)
                    acc[i][j] = fmaf(a[i], wv[j], acc[i][j]);
        }
        __syncthreads();
    }

    const int nb = n0 + tj*4;
    float bv[4] = {0.f, 0.f, 0.f, 0.f};
    #pragma unroll
    for (int e = 0; e < 4; ++e) if (nb + e < N) bv[e] = bias[nb + e];

    if (!G0OUT) {
        #pragma unroll
        for (int i = 0; i < 8; ++i) {
            const long m = m0 + ti*8 + i;
            if (nb + 3 < N) {
                float4 v;
                v.x = fmaxf(acc[i][0] + bv[0], 0.f);
                v.y = fmaxf(acc[i][1] + bv[1], 0.f);
                v.z = fmaxf(acc[i][2] + bv[2], 0.f);
                v.w = fmaxf(acc[i][3] + bv[3], 0.f);
                *(float4*)(C + m*(long)ldc + nb) = v;
            } else {
                #pragma unroll
                for (int j = 0; j < 4; ++j)
                    if (nb + j < N)
                        C[m*(long)ldc + nb + j] = fmaxf(acc[i][j] + bv[j], 0.f);
            }
        }
    } else {
        #pragma unroll
        for (int i = 0; i < 8; ++i) {
            const int m = m0 + ti*8 + i;
            #pragma unroll
            for (int j = 0; j < 4; ++j) {
                const int k = nb + j;
                if (k < 224) {
                    float v = 0.f;
                    if (k < N) v = fmaxf(acc[i][j] + bv[j], 0.f);
                    const half_t hi = (half_t)v;
                    const half_t lo = (half_t)(v - (float)hi);
                    const int kc = k >> 5, klo = k & 31;
                    const int h = klo >> 4, rm = klo & 15;
                    const int gg = rm >> 2, rr = rm & 3;
                    const size_t idx =
                        ((size_t)((m >> 4)*7 + kc)*64 + (gg << 4) + (m & 15))*8
                        + h*4 + rr;
                    g0h[idx] = hi;
                    g0l[idx] = lo;
                }
            }
        }
    }
}

__global__ __launch_bounds__(256, 4) void fc1_k(
        const float* __restrict__ A, const float* __restrict__ W,
        const float* __restrict__ bias, float* __restrict__ C) {
    __shared__ float pool[32*132 + 32*64];
    gemm_body<false>(pool, blockIdx.x, blockIdx.y, A, 200, W, bias, C, 400,
                     NB, 400, 200, nullptr, nullptr);
}

__global__ __launch_bounds__(256, 4) void fc2_k(
        const float* __restrict__ A, const float* __restrict__ W,
        const float* __restrict__ bias,
        half_t* __restrict__ g0h, half_t* __restrict__ g0l) {
    __shared__ float pool[32*132 + 32*64];
    gemm_body<true>(pool, blockIdx.x & 3, blockIdx.x >> 2, A, 400, W, bias,
                    nullptr, 0, NB, 200, 400, g0h, g0l);
}

// ---------------------------------------------------------------------------
// head_k v4: fused chain, split-f16 MFMA, double-buffered staging; mb=1
// (16 batch rows/wave), 4 blocks/CU. grid 1664, XCD-swizzled.
// ---------------------------------------------------------------------------
#define MFMA(a, b, c) __builtin_amdgcn_mfma_f32_16x16x32_f16(a, b, c, 0, 0, 0)

__global__ __launch_bounds__(256, 4) void head_k(
        const half_t* __restrict__ g0h, const half_t* __restrict__ g0l,
        const half_t* __restrict__ w1h, const half_t* __restrict__ w1l,
        const half_t* __restrict__ w2h, const half_t* __restrict__ w2l,
        const half_t* __restrict__ w3h, const half_t* __restrict__ w3l,
        const half_t* __restrict__ w4h, const half_t* __restrict__ w4l,
        const float* __restrict__ b1, const float* __restrict__ b2,
        const float* __restrict__ b3, const float* __restrict__ b4,
        float* __restrict__ out) {
    constexpr int CH = 18*512;
    __shared__ half_t wb[2*CH];
    __shared__ float bl[270];
    const int bid = blockIdx.x;
    const int cx  = bid & 7;
    const int kq  = bid >> 3;
    const int r   = ((kq >> 4) << 3) + cx;
    if (r >= NR) return;
    const int mt  = kq & 15;
    const int tid = threadIdx.x;
    if (tid < 140) bl[tid]       = b1[(size_t)r*140 + tid];
    if (tid < 84)  bl[140 + tid] = b2[(size_t)r*84  + tid];
    if (tid < 42)  bl[224 + tid] = b3[(size_t)r*42  + tid];
    if (tid < 4)   bl[266 + tid] = b4[(size_t)r*4   + tid];
    const int w = tid >> 6, l = tid & 63;
    const int g4 = ((l >> 4) & 3) * 4;
    const int mb0 = mt*4 + w;
    const size_t loff = (size_t)l * 8;

    auto stage1 = [&](int kc, half_t* buf) {
        const half_t* hs = w1h + ((size_t)r*7 + kc)*9*512;
        const half_t* ls = w1l + ((size_t)r*7 + kc)*9*512;
        #pragma unroll
        for (int p0 = 0; p0 < 3; ++p0) {
            const int p = w + p0*4;
            if (p < 9) {
                GLDS(hs + (size_t)p*512 + loff, buf + p*512);
                GLDS(ls + (size_t)p*512 + loff, buf + (9+p)*512);
            }
        }
    };
    auto stage2 = [&](int kc, half_t* buf) {
        const half_t* hs = w2h + ((size_t)r*5 + kc)*6*512;
        const half_t* ls = w2l + ((size_t)r*5 + kc)*6*512;
        #pragma unroll
        for (int p0 = 0; p0 < 2; ++p0) {
            const int p = w + p0*4;
            if (p < 6) {
                GLDS(hs + (size_t)p*512 + loff, buf + p*512);
                GLDS(ls + (size_t)p*512 + loff, buf + (6+p)*512);
            }
        }
    };
    auto stage3 = [&](int kc, half_t* buf) {
        const half_t* hs = w3h + ((size_t)r*3 + kc)*3*512;
        const half_t* ls = w3l + ((size_t)r*3 + kc)*3*512;
        if (w < 3) {
            GLDS(hs + (size_t)w*512 + loff, buf + w*512);
            GLDS(ls + (size_t)w*512 + loff, buf + (3+w)*512);
        }
    };

    // L1
    f16x8 bhv[2], blv[2];
    stage1(0, wb);
    {
        const size_t bo = ((size_t)mb0*7 + 0)*512 + loff;
        bhv[0] = *(const f16x8*)(g0h + bo);
        blv[0] = *(const f16x8*)(g0l + bo);
    }
    __syncthreads();
    f32x4 a1[9] = {};
    #pragma unroll
    for (int kc = 0; kc < 7; ++kc) {
        const half_t* cur = wb + (kc & 1)*CH;
        if (kc < 6) {
            stage1(kc+1, wb + ((kc+1) & 1)*CH);
            const size_t bo = ((size_t)mb0*7 + kc + 1)*512 + loff;
            bhv[(kc+1)&1] = *(const f16x8*)(g0h + bo);
            blv[(kc+1)&1] = *(const f16x8*)(g0l + bo);
        } else {
            stage2(0, wb + CH);
        }
        #pragma unroll
        for (int nf = 0; nf < 9; ++nf) {
            const f16x8 wh = *(const f16x8*)(cur + nf*512 + loff);
            const f16x8 wl = *(const f16x8*)(cur + (9+nf)*512 + loff);
            a1[nf] = MFMA(wh, bhv[kc&1], a1[nf]);
            a1[nf] = MFMA(wh, blv[kc&1], a1[nf]);
            a1[nf] = MFMA(wl, bhv[kc&1], a1[nf]);
        }
        __syncthreads();
    }
    f16x8 b2h[5], b2l[5];
    #pragma unroll
    for (int kc = 0; kc < 5; ++kc)
        #pragma unroll
        for (int h = 0; h < 2; ++h) {
            const int nf = kc*2 + h;
            #pragma unroll
            for (int rr = 0; rr < 4; ++rr) {
                float v = 0.f;
                if (nf < 9) {
                    const int n = nf*16 + g4 + rr;
                    v = (n < 140) ? fmaxf(a1[nf][rr] + bl[n], 0.f) : 0.f;
                }
                const half_t hi = (half_t)v;
                const half_t lo = (half_t)(v - (float)hi);
                b2h[kc][h*4+rr] = hi;
                b2l[kc][h*4+rr] = lo;
            }
        }
    // L2
    f32x4 a2[6] = {};
    #pragma unroll
    for (int kc = 0; kc < 5; ++kc) {
        const half_t* cur = wb + (((kc+1) & 1))*CH;
        if (kc < 4) stage2(kc+1, wb + (kc & 1)*CH);
        else        stage3(0,    wb + (kc & 1)*CH);
        #pragma unroll
        for (int nf = 0; nf < 6; ++nf) {
            const f16x8 wh = *(const f16x8*)(cur + nf*512 + loff);
            const f16x8 wl = *(const f16x8*)(cur + (6+nf)*512 + loff);
            a2[nf] = MFMA(wh, b2h[kc], a2[nf]);
            a2[nf] = MFMA(wh, b2l[kc], a2[nf]);
            a2[nf] = MFMA(wl, b2h[kc], a2[nf]);
        }
        __syncthreads();
    }
    f16x8 b3h[3], b3l[3];
    #pragma unroll
    for (int kc = 0; kc < 3; ++kc)
        #pragma unroll
        for (int h = 0; h < 2; ++h) {
            const int nf = kc*2 + h;
            #pragma unroll
            for (int rr = 0; rr < 4; ++rr) {
                float v = 0.f;
                if (nf < 6) {
                    const int n = nf*16 + g4 + rr;
                    v = (n < 84) ? fmaxf(a2[nf][rr] + bl[140 + n], 0.f) : 0.f;
                }
                const half_t hi = (half_t)v;
                const half_t lo = (half_t)(v - (float)hi);
                b3h[kc][h*4+rr] = hi;
                b3l[kc][h*4+rr] = lo;
            }
        }
    // L3
    f32x4 a3[3] = {};
    #pragma unroll
    for (int kc = 0; kc < 3; ++kc) {
        const half_t* cur = wb + (kc & 1)*CH;
        if (kc < 2) stage3(kc+1, wb + ((kc+1) & 1)*CH);
        #pragma unroll
        for (int nf = 0; nf < 3; ++nf) {
            const f16x8 wh = *(const f16x8*)(cur + nf*512 + loff);
            const f16x8 wl = *(const f16x8*)(cur + (3+nf)*512 + loff);
            a3[nf] = MFMA(wh, b3h[kc], a3[nf]);
            a3[nf] = MFMA(wh, b3l[kc], a3[nf]);
            a3[nf] = MFMA(wl, b3h[kc], a3[nf]);
        }
        __syncthreads();
    }
    f16x8 b4h[2], b4l[2];
    #pragma unroll
    for (int kc = 0; kc < 2; ++kc)
        #pragma unroll
        for (int h = 0; h < 2; ++h) {
            const int nf = kc*2 + h;
            #pragma unroll
            for (int rr = 0; rr < 4; ++rr) {
                float v = 0.f;
                if (nf < 3) {
                    const int n = nf*16 + g4 + rr;
                    v = (n < 42) ? fmaxf(a3[nf][rr] + bl[224 + n], 0.f) : 0.f;
                }
                const half_t hi = (half_t)v;
                const half_t lo = (half_t)(v - (float)hi);
                b4h[kc][h*4+rr] = hi;
                b4l[kc][h*4+rr] = lo;
            }
        }
    // L4
    f32x4 a4 = {};
    #pragma unroll
    for (int kc = 0; kc < 2; ++kc) {
        const size_t wo = ((size_t)r*2 + kc)*512 + loff;
        const f16x8 wh = *(const f16x8*)(w4h + wo);
        const f16x8 wl = *(const f16x8*)(w4l + wo);
        a4 = MFMA(wh, b4h[kc], a4);
        a4 = MFMA(wh, b4l[kc], a4);
        a4 = MFMA(wl, b4h[kc], a4);
    }
    if ((l >> 4) == 0) {
        const int b = mb0*16 + (l & 15);
        float4 o;
        o.x = a4[0] + bl[266];
        o.y = a4[1] + bl[267];
        o.z = a4[2] + bl[268];
        o.w = a4[3] + bl[269];
        *(float4*)(out + (size_t)b*400 + r*4) = o;
    }
}

extern "C" void kernel_launch(void* const* d_in, const int* in_sizes, int n_in,
                              void* d_out, int out_size, void* d_ws, size_t ws_size,
                              hipStream_t stream) {
    const float* x    = (const float*)d_in[0];
    const float* c1w  = (const float*)d_in[1];
    const float* c1b  = (const float*)d_in[2];
    const float* c2w  = (const float*)d_in[3];
    const float* c2b  = (const float*)d_in[4];
    const float* c3w  = (const float*)d_in[5];
    const float* c3b  = (const float*)d_in[6];
    const float* fc1w = (const float*)d_in[7];
    const float* fc1b = (const float*)d_in[8];
    const float* fc2w = (const float*)d_in[9];
    const float* fc2b = (const float*)d_in[10];
    const float* h1w  = (const float*)d_in[11];
    const float* h1b  = (const float*)d_in[12];
    const float* h2w  = (const float*)d_in[13];
    const float* h2b  = (const float*)d_in[14];
    const float* h3w  = (const float*)d_in[15];
    const float* h3b  = (const float*)d_in[16];
    const float* h4w  = (const float*)d_in[17];
    const float* h4b  = (const float*)d_in[18];
    float* out = (float*)d_out;

    char* ws = (char*)d_ws;
    size_t o = 0;
    float* t2 = (float*)(ws + o); o += (size_t)NB*4*484*4;
    float* t3 = (float*)(ws + o); o += (size_t)NB*200*4;
    float* f1 = (float*)(ws + o); o += (size_t)NB*400*4;
    half_t* g0h = (half_t*)(ws + o); o += (size_t)64*7*512*2;
    half_t* g0l = (half_t*)(ws + o); o += (size_t)64*7*512*2;
    half_t* w1h = (half_t*)(ws + o); o += (size_t)NR*7*9*512*2;
    half_t* w1l = (half_t*)(ws + o); o += (size_t)NR*7*9*512*2;
    half_t* w2h = (half_t*)(ws + o); o += (size_t)NR*5*6*512*2;
    half_t* w2l = (half_t*)(ws + o); o += (size_t)NR*5*6*512*2;
    half_t* w3h = (half_t*)(ws + o); o += (size_t)NR*3*3*512*2;
    half_t* w3l = (half_t*)(ws + o); o += (size_t)NR*3*3*512*2;
    half_t* w4h = (half_t*)(ws + o); o += (size_t)NR*2*1*512*2;
    half_t* w4l = (half_t*)(ws + o); o += (size_t)NR*2*1*512*2;

    conv12ws_k<<<NWSP + NB*4, 256, 0, stream>>>(x, c1w, c1b, c2w, c2b, t2,
        h1w, h2w, h3w, h4w, w1h, w1l, w2h, w2l, w3h, w3l, w4h, w4l);
    conv3_k<<<NB, 256, 0, stream>>>(t2, c3w, c3b, t3);
    fc1_k<<<dim3(7, 8), 256, 0, stream>>>(t3, fc1w, fc1b, f1);
    fc2_k<<<32, 256, 0, stream>>>(f1, fc2w, fc2b, g0h, g0l);
    head_k<<<1664, 256, 0, stream>>>(
        g0h, g0l, w1h, w1l, w2h, w2l, w3h, w3l, w4h, w4l,
        h1b, h2b, h3b, h4b, out);

    (void)in_sizes; (void)n_in; (void)out_size; (void)ws_size;
}

// Round 17
// 177.672 us; speedup vs baseline: 1.0679x; 1.0679x over previous
//
#include <hip/hip_runtime.h>

#define NB 1024
#define NR 100

typedef _Float16 half_t;
typedef half_t f16x8 __attribute__((ext_vector_type(8)));
typedef float f32x4 __attribute__((ext_vector_type(4)));
typedef float f32x2 __attribute__((ext_vector_type(2)));

__device__ __forceinline__ int kmap2(int g, int j) {
    return g*4 + (j & 3) + ((j >> 2) << 4);
}

__device__ __forceinline__ f32x2 pkfma(f32x2 a, float s, f32x2 c) {
    return __builtin_elementwise_fma(a, (f32x2){s, s}, c);
}

// async global->LDS, 16B per lane; LDS dest = base + lane*16 (HW behavior)
#define GLDS(gsrc, ldst) \
    __builtin_amdgcn_global_load_lds( \
        (const __attribute__((address_space(1))) void*)(gsrc), \
        (__attribute__((address_space(3))) void*)(ldst), 16, 0, 0)

// ---------------------------------------------------------------------------
// conv12: fused conv1 -> conv2 per image quadrant (4096 blocks).
// img staged parity-split with float2 fast path for interior rows.
// ---------------------------------------------------------------------------
#define EOFF 2268
#define IO   1568
__global__ __launch_bounds__(256, 5) void conv12_k(const float* __restrict__ x,
        const float* __restrict__ c1w, const float* __restrict__ b1c,
        const float* __restrict__ c2w, const float* __restrict__ b2c,
        float* __restrict__ out) {
    __shared__ float img[3136];
    __shared__ float c1p[4374];
    const int bid = blockIdx.x;
    const int tid = threadIdx.x;
    const int b  = bid >> 2;
    const int qy = (bid >> 1) & 1, qx = bid & 1;
    const int R0 = 44*qy - 1, C0 = 44*qx - 1;
    const float* xb = x + (size_t)b * 9604;

    // stage 56 rows x 28 col-pairs; pair i covers gc = C0+2i, C0+2i+1.
    // C0 is odd => gc(even idx)=odd: pairs are (odd,even) -> never a single
    // aligned float2 in x; but (C0+2i+1, C0+2i+2) IS aligned. Use the
    // shifted fast path: load aligned pair for elements 1,2 of each triple.
    // Simpler robust split: element j of row handled scalar if at border.
    for (int i = tid; i < 1568; i += 256) {       // 56 rows x 28 pairs
        const int rr = i / 28, pi = i - rr*28;
        const int gr = R0 + rr;
        const int gc0 = C0 + 2*pi;                // even-plane source col
        const int gc1 = gc0 + 1;                  // odd-plane source col
        float v0 = 0.f, v1 = 0.f;
        if (gr >= 0 && gr < 98) {
            const float* row = xb + (size_t)gr*98;
            if (gc0 >= 0 && gc1 < 98) {           // interior: both valid
                v0 = row[gc0];
                v1 = row[gc1];
            } else {
                if (gc0 >= 0 && gc0 < 98) v0 = row[gc0];
                if (gc1 >= 0 && gc1 < 98) v1 = row[gc1];
            }
        }
        img[rr*28 + pi]      = v0;
        img[IO + rr*28 + pi] = v1;
    }
    __syncthreads();

    // conv1
    for (int pos = tid; pos < 729; pos += 256) {
        const int py = pos / 27, px = pos - py*27;
        float p[4][4];
        #pragma unroll
        for (int u = 0; u < 4; ++u) {
            const int ro = (2*py + u)*28;
            p[u][0] = img[ro + px];
            p[u][2] = img[ro + px + 1];
            p[u][1] = img[IO + ro + px];
            p[u][3] = img[IO + ro + px + 1];
        }
        f32x2 a2[3][4];
        #pragma unroll
        for (int g = 0; g < 3; ++g) {
            const f32x2 bv = {b1c[g*2], b1c[g*2+1]};
            a2[g][0] = a2[g][1] = a2[g][2] = a2[g][3] = bv;
        }
        #pragma unroll
        for (int ky = 0; ky < 3; ++ky)
            #pragma unroll
            for (int kx = 0; kx < 3; ++kx) {
                const int k = ky*3 + kx;
                const float q0 = p[ky  ][kx], q1 = p[ky  ][kx+1];
                const float q2 = p[ky+1][kx], q3 = p[ky+1][kx+1];
                #pragma unroll
                for (int g = 0; g < 3; ++g) {
                    const f32x2 wv = {c1w[(g*2)*9 + k], c1w[(g*2+1)*9 + k]};
                    a2[g][0] = pkfma(wv, q0, a2[g][0]);
                    a2[g][1] = pkfma(wv, q1, a2[g][1]);
                    a2[g][2] = pkfma(wv, q2, a2[g][2]);
                    a2[g][3] = pkfma(wv, q3, a2[g][3]);
                }
            }
        const int par = px & 1, pi = px >> 1;
        #pragma unroll
        for (int g = 0; g < 3; ++g) {
            const float m0 = fmaxf(fmaxf(a2[g][0].x, a2[g][1].x),
                                   fmaxf(a2[g][2].x, a2[g][3].x));
            const float m1 = fmaxf(fmaxf(a2[g][0].y, a2[g][1].y),
                                   fmaxf(a2[g][2].y, a2[g][3].y));
            const int e0 = par ? (EOFF + ((2*g    )*27 + py)*13 + pi)
                               : (((2*g    )*27 + py)*14 + pi);
            const int e1 = par ? (EOFF + ((2*g + 1)*27 + py)*13 + pi)
                               : (((2*g + 1)*27 + py)*14 + pi);
            c1p[e0] = fmaxf(m0, 0.f);
            c1p[e1] = fmaxf(m1, 0.f);
        }
    }
    __syncthreads();

    // conv2: ic-split, 4 oc per active lane
    const int wv_ = tid >> 6;
    const int ich = __builtin_amdgcn_readfirstlane(tid >> 7);
    const int unit = ((wv_ & 1) << 6) | (tid & 63);
    const bool act = unit < 121;
    const int py = act ? unit / 11 : 0;
    const int px = act ? unit - py*11 : 0;
    const int y0 = 2*py;

    f32x2 acc[2][2][2] = {};
    if (act) {
        #pragma unroll
        for (int ic3 = 0; ic3 < 3; ++ic3) {
            const int ic = ich*3 + ic3;
            const float* pe0 = c1p + (ic*27 + y0)*14 + px;
            const float* po0 = c1p + EOFF + (ic*27 + y0)*13 + px;
            #pragma unroll
            for (int u = 0; u < 7; ++u) {
                const float* pe = pe0 + u*14;
                const float* po = po0 + u*13;
                float pr[7];
                pr[0] = pe[0]; pr[2] = pe[1]; pr[4] = pe[2]; pr[6] = pe[3];
                pr[1] = po[0]; pr[3] = po[1]; pr[5] = po[2];
                #pragma unroll
                for (int dy = 0; dy < 2; ++dy) {
                    const int ky = u - dy;
                    if (ky < 0 || ky > 5) continue;
                    #pragma unroll
                    for (int kx = 0; kx < 6; ++kx) {
                        const int idx = ic*36 + ky*6 + kx;
                        const f32x2 w0 = {c2w[idx],       c2w[216 + idx]};
                        const f32x2 w1 = {c2w[432 + idx], c2w[648 + idx]};
                        acc[0][dy][0] = pkfma(w0, pr[0+kx], acc[0][dy][0]);
                        acc[0][dy][1] = pkfma(w0, pr[1+kx], acc[0][dy][1]);
                        acc[1][dy][0] = pkfma(w1, pr[0+kx], acc[1][dy][0]);
                        acc[1][dy][1] = pkfma(w1, pr[1+kx], acc[1][dy][1]);
                    }
                }
            }
        }
    }
    float* pbuf = img;
    if (act && ich == 1) {
        #pragma unroll
        for (int p = 0; p < 2; ++p)
            #pragma unroll
            for (int dy = 0; dy < 2; ++dy)
                #pragma unroll
                for (int dx = 0; dx < 2; ++dx) {
                    const int j = ((p*2 + dy)*2 + dx)*2;
                    pbuf[(j    )*128 + unit] = acc[p][dy][dx].x;
                    pbuf[(j + 1)*128 + unit] = acc[p][dy][dx].y;
                }
    }
    __syncthreads();
    if (act && ich == 0) {
        #pragma unroll
        for (int p = 0; p < 2; ++p)
            #pragma unroll
            for (int dy = 0; dy < 2; ++dy)
                #pragma unroll
                for (int dx = 0; dx < 2; ++dx) {
                    const int j = ((p*2 + dy)*2 + dx)*2;
                    acc[p][dy][dx].x += pbuf[(j    )*128 + unit];
                    acc[p][dy][dx].y += pbuf[(j + 1)*128 + unit];
                }
        const int PY = qy*11 + py, PX = qx*11 + px;
        #pragma unroll
        for (int p = 0; p < 2; ++p) {
            const float m0 = fmaxf(fmaxf(acc[p][0][0].x, acc[p][0][1].x),
                                   fmaxf(acc[p][1][0].x, acc[p][1][1].x)) + b2c[p*2];
            const float m1 = fmaxf(fmaxf(acc[p][0][0].y, acc[p][0][1].y),
                                   fmaxf(acc[p][1][0].y, acc[p][1][1].y)) + b2c[p*2+1];
            out[(((size_t)b*4 + p*2    )*22 + PY)*22 + PX] = fmaxf(m0, 0.f);
            out[(((size_t)b*4 + p*2 + 1)*22 + PY)*22 + PX] = fmaxf(m1, 0.f);
        }
    }
}

// ---------------------------------------------------------------------------
// conv3: in[B,4,22,22] -> out[B,200]
// ---------------------------------------------------------------------------
__global__ __launch_bounds__(256) void conv3_k(const float* __restrict__ in,
        const float* __restrict__ w, const float* __restrict__ bias,
        float* __restrict__ out) {
    __shared__ float sm[1936];
    const int b = blockIdx.x;
    const int tid = threadIdx.x;
    const float* src = in + (size_t)b * 1936;
    for (int i = tid; i < 484; i += 256)
        ((float4*)sm)[i] = ((const float4*)src)[i];
    __syncthreads();
    if (tid < 200) {
        const int c = tid / 100;
        const int rem = tid % 100;
        const int py = rem / 10, px = rem % 10;
        const int y0 = 2*py, x0 = 2*px;
        float a0, a1, a2, a3;
        a0 = a1 = a2 = a3 = bias[c];
        #pragma unroll
        for (int ic = 0; ic < 4; ++ic) {
            float p[4][4];
            const float* base = sm + ic*484 + y0*22 + x0;
            #pragma unroll
            for (int u = 0; u < 4; ++u)
                #pragma unroll
                for (int v = 0; v < 4; ++v)
                    p[u][v] = base[u*22 + v];
            #pragma unroll
            for (int ky = 0; ky < 3; ++ky) {
                #pragma unroll
                for (int kx = 0; kx < 3; ++kx) {
                    const float wv = w[(c*4 + ic)*9 + ky*3 + kx];
                    a0 = fmaf(wv, p[ky  ][kx  ], a0);
                    a1 = fmaf(wv, p[ky  ][kx+1], a1);
                    a2 = fmaf(wv, p[ky+1][kx  ], a2);
                    a3 = fmaf(wv, p[ky+1][kx+1], a3);
                }
            }
        }
        float m = fmaxf(fmaxf(a0, a1), fmaxf(a2, a3));
        out[(size_t)b*200 + tid] = fmaxf(m, 0.f);
    }
}

// ---------------------------------------------------------------------------
// gemm body (fc1 / fc2). G0OUT: packed f16 hi/lo fragment planes + pad fill.
// ---------------------------------------------------------------------------
template<bool G0OUT>
__device__ __forceinline__ void gemm_body(float* pool, int bx, int by,
        const float* __restrict__ A, int lda,
        const float* __restrict__ W, const float* __restrict__ bias,
        float* __restrict__ C, int ldc,
        int M, int N, int K,
        half_t* __restrict__ g0h, half_t* __restrict__ g0l) {
    float (*As)[132] = (float(*)[132])pool;
    float* Ws = pool + 32*132;
    const int m0 = by * 128;
    const int n0 = bx * 64;
    const int tid = threadIdx.x;
    const int ti = tid >> 4, tj = tid & 15;
    float acc[8][4];
    #pragma unroll
    for (int i = 0; i < 8; ++i)
        #pragma unroll
        for (int j = 0; j < 4; ++j) acc[i][j] = 0.f;

    for (int k0 = 0; k0 < K; k0 += 32) {
        #pragma unroll
        for (int i = 0; i < 4; ++i) {
            const int f = tid + i*256;
            const int m = f >> 3, kg = f & 7;
            const int kk = kg*4;
            float4 v = make_float4(0.f, 0.f, 0.f, 0.f);
            if (k0 + kk < K)
                v = *(const float4*)(A + (long)(m0 + m)*lda + k0 + kk);
            As[kk+0][m] = v.x;
            As[kk+1][m] = v.y;
            As[kk+2][m] = v.z;
            As[kk+3][m] = v.w;
        }
        #pragma unroll
        for (int i = 0; i < 2; ++i) {
            const int f = tid + i*256;
            const int kk = f >> 4, cg = f & 15;
            const int n = n0 + cg*4;
            float4 v = make_float4(0.f, 0.f, 0.f, 0.f);
            if (k0 + kk < K) {
                const float* wp = W + (long)(k0 + kk)*N;
                if (n + 3 < N) v = *(const float4*)(wp + n);
                else {
                    if (n+0 < N) v.x = wp[n+0];
                    if (n+1 < N) v.y = wp[n+1];
                    if (n+2 < N) v.z = wp[n+2];
                }
            }
            *(float4*)&Ws[kk*64 + cg*4] = v;
        }
        __syncthreads();
        #pragma unroll
        for (int kk = 0; kk < 32; ++kk) {
            float a[8], wv[4];
            *(float4*)&a[0] = *(const float4*)&As[kk][ti*8];
            *(float4*)&a[4] = *(const float4*)&As[kk][ti*8 + 4];
            *(float4*)&wv[0] = *(const float4*)&Ws[kk*64 + tj*4];
            #pragma unroll
            for (int i = 0; i < 8; ++i)
                #pragma unroll
                for (int j = 0; j < 4; ++j)
                    acc[i][j] = fmaf(a[i], wv[j], acc[i][j]);
        }
        __syncthreads();
    }

    const int nb = n0 + tj*4;
    float bv[4] = {0.f, 0.f, 0.f, 0.f};
    #pragma unroll
    for (int e = 0; e < 4; ++e) if (nb + e < N) bv[e] = bias[nb + e];

    if (!G0OUT) {
        #pragma unroll
        for (int i = 0; i < 8; ++i) {
            const long m = m0 + ti*8 + i;
            if (nb + 3 < N) {
                float4 v;
                v.x = fmaxf(acc[i][0] + bv[0], 0.f);
                v.y = fmaxf(acc[i][1] + bv[1], 0.f);
                v.z = fmaxf(acc[i][2] + bv[2], 0.f);
                v.w = fmaxf(acc[i][3] + bv[3], 0.f);
                *(float4*)(C + m*(long)ldc + nb) = v;
            } else {
                #pragma unroll
                for (int j = 0; j < 4; ++j)
                    if (nb + j < N)
                        C[m*(long)ldc + nb + j] = fmaxf(acc[i][j] + bv[j], 0.f);
            }
        }
    } else {
        #pragma unroll
        for (int i = 0; i < 8; ++i) {
            const int m = m0 + ti*8 + i;
            #pragma unroll
            for (int j = 0; j < 4; ++j) {
                const int k = nb + j;
                if (k < 224) {
                    float v = 0.f;
                    if (k < N) v = fmaxf(acc[i][j] + bv[j], 0.f);
                    const half_t hi = (half_t)v;
                    const half_t lo = (half_t)(v - (float)hi);
                    const int kc = k >> 5, klo = k & 31;
                    const int h = klo >> 4, rm = klo & 15;
                    const int gg = rm >> 2, rr = rm & 3;
                    const size_t idx =
                        ((size_t)((m >> 4)*7 + kc)*64 + (gg << 4) + (m & 15))*8
                        + h*4 + rr;
                    g0h[idx] = hi;
                    g0l[idx] = lo;
                }
            }
        }
    }
}

__global__ __launch_bounds__(256, 4) void fc1_k(
        const float* __restrict__ A, const float* __restrict__ W,
        const float* __restrict__ bias, float* __restrict__ C) {
    __shared__ float pool[32*132 + 32*64];
    gemm_body<false>(pool, blockIdx.x, blockIdx.y, A, 200, W, bias, C, 400,
                     NB, 400, 200, nullptr, nullptr);
}

// ---------------------------------------------------------------------------
// fc2ws: blocks 0..31 = fc2 gemm (G0OUT); blocks 32..1731 = wsplit (17 x 100).
// (round-14 proven placement)
// ---------------------------------------------------------------------------
__global__ __launch_bounds__(256, 4) void fc2ws_k(
        const float* __restrict__ A, const float* __restrict__ W,
        const float* __restrict__ bias,
        half_t* __restrict__ g0h, half_t* __restrict__ g0l,
        const float* __restrict__ w1, const float* __restrict__ w2,
        const float* __restrict__ w3, const float* __restrict__ w4,
        half_t* __restrict__ f1h, half_t* __restrict__ f1l,
        half_t* __restrict__ f2h, half_t* __restrict__ f2l,
        half_t* __restrict__ f3h, half_t* __restrict__ f3l,
        half_t* __restrict__ f4h, half_t* __restrict__ f4l) {
    __shared__ float pool[32*132 + 32*64];
    const int bid = blockIdx.x;
    const int tid = threadIdx.x;
    if (bid < 32) {
        gemm_body<true>(pool, bid & 3, bid >> 2, A, 400, W, bias,
                        nullptr, 0, NB, 200, 400, g0h, g0l);
        return;
    }
    const int wq = bid - 32;
    const int cx = wq % 17, r = wq / 17;
    float* lds = pool;
    int K, N, KC, NF, kc;
    const float* src;
    half_t *dh, *dl;
    if (cx < 7)       { K=200; N=140; KC=7; NF=9; kc=cx;    src=w1; dh=f1h; dl=f1l; }
    else if (cx < 12) { K=140; N=84;  KC=5; NF=6; kc=cx-7;  src=w2; dh=f2h; dl=f2l; }
    else if (cx < 15) { K=84;  N=42;  KC=3; NF=3; kc=cx-12; src=w3; dh=f3h; dl=f3l; }
    else              { K=42;  N=4;   KC=2; NF=1; kc=cx-15; src=w4; dh=f4h; dl=f4l; }
    const float* sb = src + (size_t)r * K * N;
    for (int i = tid; i < 32*N; i += 256) {
        const int kk = i / N, n = i - kk*N;
        const int kg = kc*32 + kk;
        lds[kk*N + n] = (kg < K) ? sb[(size_t)kg*N + n] : 0.f;
    }
    __syncthreads();
    const size_t base = ((size_t)r*KC + kc)*NF*512;
    for (int e = tid; e < NF*512; e += 256) {
        const int nf = e >> 9, rem = e & 511;
        const int l = rem >> 3, j = rem & 7;
        const int g = l >> 4, c = l & 15;
        const int kl = kmap2(g, j);
        const int n = nf*16 + c;
        const float v = (n < N) ? lds[kl*N + n] : 0.f;
        const half_t hi = (half_t)v;
        const half_t lo = (half_t)(v - (float)hi);
        dh[base + (size_t)nf*512 + rem] = hi;
        dl[base + (size_t)nf*512 + rem] = lo;
    }
}

// ---------------------------------------------------------------------------
// head_k v4: fused chain, split-f16 MFMA, double-buffered staging; mb=1
// (16 batch rows/wave), 4 blocks/CU. grid 1664, XCD-swizzled.
// ---------------------------------------------------------------------------
#define MFMA(a, b, c) __builtin_amdgcn_mfma_f32_16x16x32_f16(a, b, c, 0, 0, 0)

__global__ __launch_bounds__(256, 4) void head_k(
        const half_t* __restrict__ g0h, const half_t* __restrict__ g0l,
        const half_t* __restrict__ w1h, const half_t* __restrict__ w1l,
        const half_t* __restrict__ w2h, const half_t* __restrict__ w2l,
        const half_t* __restrict__ w3h, const half_t* __restrict__ w3l,
        const half_t* __restrict__ w4h, const half_t* __restrict__ w4l,
        const float* __restrict__ b1, const float* __restrict__ b2,
        const float* __restrict__ b3, const float* __restrict__ b4,
        float* __restrict__ out) {
    constexpr int CH = 18*512;
    __shared__ half_t wb[2*CH];
    __shared__ float bl[270];
    const int bid = blockIdx.x;
    const int cx  = bid & 7;
    const int kq  = bid >> 3;
    const int r   = ((kq >> 4) << 3) + cx;
    if (r >= NR) return;
    const int mt  = kq & 15;
    const int tid = threadIdx.x;
    if (tid < 140) bl[tid]       = b1[(size_t)r*140 + tid];
    if (tid < 84)  bl[140 + tid] = b2[(size_t)r*84  + tid];
    if (tid < 42)  bl[224 + tid] = b3[(size_t)r*42  + tid];
    if (tid < 4)   bl[266 + tid] = b4[(size_t)r*4   + tid];
    const int w = tid >> 6, l = tid & 63;
    const int g4 = ((l >> 4) & 3) * 4;
    const int mb0 = mt*4 + w;
    const size_t loff = (size_t)l * 8;

    auto stage1 = [&](int kc, half_t* buf) {
        const half_t* hs = w1h + ((size_t)r*7 + kc)*9*512;
        const half_t* ls = w1l + ((size_t)r*7 + kc)*9*512;
        #pragma unroll
        for (int p0 = 0; p0 < 3; ++p0) {
            const int p = w + p0*4;
            if (p < 9) {
                GLDS(hs + (size_t)p*512 + loff, buf + p*512);
                GLDS(ls + (size_t)p*512 + loff, buf + (9+p)*512);
            }
        }
    };
    auto stage2 = [&](int kc, half_t* buf) {
        const half_t* hs = w2h + ((size_t)r*5 + kc)*6*512;
        const half_t* ls = w2l + ((size_t)r*5 + kc)*6*512;
        #pragma unroll
        for (int p0 = 0; p0 < 2; ++p0) {
            const int p = w + p0*4;
            if (p < 6) {
                GLDS(hs + (size_t)p*512 + loff, buf + p*512);
                GLDS(ls + (size_t)p*512 + loff, buf + (6+p)*512);
            }
        }
    };
    auto stage3 = [&](int kc, half_t* buf) {
        const half_t* hs = w3h + ((size_t)r*3 + kc)*3*512;
        const half_t* ls = w3l + ((size_t)r*3 + kc)*3*512;
        if (w < 3) {
            GLDS(hs + (size_t)w*512 + loff, buf + w*512);
            GLDS(ls + (size_t)w*512 + loff, buf + (3+w)*512);
        }
    };

    // L1
    f16x8 bhv[2], blv[2];
    stage1(0, wb);
    {
        const size_t bo = ((size_t)mb0*7 + 0)*512 + loff;
        bhv[0] = *(const f16x8*)(g0h + bo);
        blv[0] = *(const f16x8*)(g0l + bo);
    }
    __syncthreads();
    f32x4 a1[9] = {};
    #pragma unroll
    for (int kc = 0; kc < 7; ++kc) {
        const half_t* cur = wb + (kc & 1)*CH;
        if (kc < 6) {
            stage1(kc+1, wb + ((kc+1) & 1)*CH);
            const size_t bo = ((size_t)mb0*7 + kc + 1)*512 + loff;
            bhv[(kc+1)&1] = *(const f16x8*)(g0h + bo);
            blv[(kc+1)&1] = *(const f16x8*)(g0l + bo);
        } else {
            stage2(0, wb + CH);
        }
        #pragma unroll
        for (int nf = 0; nf < 9; ++nf) {
            const f16x8 wh = *(const f16x8*)(cur + nf*512 + loff);
            const f16x8 wl = *(const f16x8*)(cur + (9+nf)*512 + loff);
            a1[nf] = MFMA(wh, bhv[kc&1], a1[nf]);
            a1[nf] = MFMA(wh, blv[kc&1], a1[nf]);
            a1[nf] = MFMA(wl, bhv[kc&1], a1[nf]);
        }
        __syncthreads();
    }
    f16x8 b2h[5], b2l[5];
    #pragma unroll
    for (int kc = 0; kc < 5; ++kc)
        #pragma unroll
        for (int h = 0; h < 2; ++h) {
            const int nf = kc*2 + h;
            #pragma unroll
            for (int rr = 0; rr < 4; ++rr) {
                float v = 0.f;
                if (nf < 9) {
                    const int n = nf*16 + g4 + rr;
                    v = (n < 140) ? fmaxf(a1[nf][rr] + bl[n], 0.f) : 0.f;
                }
                const half_t hi = (half_t)v;
                const half_t lo = (half_t)(v - (float)hi);
                b2h[kc][h*4+rr] = hi;
                b2l[kc][h*4+rr] = lo;
            }
        }
    // L2
    f32x4 a2[6] = {};
    #pragma unroll
    for (int kc = 0; kc < 5; ++kc) {
        const half_t* cur = wb + (((kc+1) & 1))*CH;
        if (kc < 4) stage2(kc+1, wb + (kc & 1)*CH);
        else        stage3(0,    wb + (kc & 1)*CH);
        #pragma unroll
        for (int nf = 0; nf < 6; ++nf) {
            const f16x8 wh = *(const f16x8*)(cur + nf*512 + loff);
            const f16x8 wl = *(const f16x8*)(cur + (6+nf)*512 + loff);
            a2[nf] = MFMA(wh, b2h[kc], a2[nf]);
            a2[nf] = MFMA(wh, b2l[kc], a2[nf]);
            a2[nf] = MFMA(wl, b2h[kc], a2[nf]);
        }
        __syncthreads();
    }
    f16x8 b3h[3], b3l[3];
    #pragma unroll
    for (int kc = 0; kc < 3; ++kc)
        #pragma unroll
        for (int h = 0; h < 2; ++h) {
            const int nf = kc*2 + h;
            #pragma unroll
            for (int rr = 0; rr < 4; ++rr) {
                float v = 0.f;
                if (nf < 6) {
                    const int n = nf*16 + g4 + rr;
                    v = (n < 84) ? fmaxf(a2[nf][rr] + bl[140 + n], 0.f) : 0.f;
                }
                const half_t hi = (half_t)v;
                const half_t lo = (half_t)(v - (float)hi);
                b3h[kc][h*4+rr] = hi;
                b3l[kc][h*4+rr] = lo;
            }
        }
    // L3
    f32x4 a3[3] = {};
    #pragma unroll
    for (int kc = 0; kc < 3; ++kc) {
        const half_t* cur = wb + (kc & 1)*CH;
        if (kc < 2) stage3(kc+1, wb + ((kc+1) & 1)*CH);
        #pragma unroll
        for (int nf = 0; nf < 3; ++nf) {
            const f16x8 wh = *(const f16x8*)(cur + nf*512 + loff);
            const f16x8 wl = *(const f16x8*)(cur + (3+nf)*512 + loff);
            a3[nf] = MFMA(wh, b3h[kc], a3[nf]);
            a3[nf] = MFMA(wh, b3l[kc], a3[nf]);
            a3[nf] = MFMA(wl, b3h[kc], a3[nf]);
        }
        __syncthreads();
    }
    f16x8 b4h[2], b4l[2];
    #pragma unroll
    for (int kc = 0; kc < 2; ++kc)
        #pragma unroll
        for (int h = 0; h < 2; ++h) {
            const int nf = kc*2 + h;
            #pragma unroll
            for (int rr = 0; rr < 4; ++rr) {
                float v = 0.f;
                if (nf < 3) {
                    const int n = nf*16 + g4 + rr;
                    v = (n < 42) ? fmaxf(a3[nf][rr] + bl[224 + n], 0.f) : 0.f;
                }
                const half_t hi = (half_t)v;
                const half_t lo = (half_t)(v - (float)hi);
                b4h[kc][h*4+rr] = hi;
                b4l[kc][h*4+rr] = lo;
            }
        }
    // L4
    f32x4 a4 = {};
    #pragma unroll
    for (int kc = 0; kc < 2; ++kc) {
        const size_t wo = ((size_t)r*2 + kc)*512 + loff;
        const f16x8 wh = *(const f16x8*)(w4h + wo);
        const f16x8 wl = *(const f16x8*)(w4l + wo);
        a4 = MFMA(wh, b4h[kc], a4);
        a4 = MFMA(wh, b4l[kc], a4);
        a4 = MFMA(wl, b4h[kc], a4);
    }
    if ((l >> 4) == 0) {
        const int b = mb0*16 + (l & 15);
        float4 o;
        o.x = a4[0] + bl[266];
        o.y = a4[1] + bl[267];
        o.z = a4[2] + bl[268];
        o.w = a4[3] + bl[269];
        *(float4*)(out + (size_t)b*400 + r*4) = o;
    }
}

extern "C" void kernel_launch(void* const* d_in, const int* in_sizes, int n_in,
                              void* d_out, int out_size, void* d_ws, size_t ws_size,
                              hipStream_t stream) {
    const float* x    = (const float*)d_in[0];
    const float* c1w  = (const float*)d_in[1];
    const float* c1b  = (const float*)d_in[2];
    const float* c2w  = (const float*)d_in[3];
    const float* c2b  = (const float*)d_in[4];
    const float* c3w  = (const float*)d_in[5];
    const float* c3b  = (const float*)d_in[6];
    const float* fc1w = (const float*)d_in[7];
    const float* fc1b = (const float*)d_in[8];
    const float* fc2w = (const float*)d_in[9];
    const float* fc2b = (const float*)d_in[10];
    const float* h1w  = (const float*)d_in[11];
    const float* h1b  = (const float*)d_in[12];
    const float* h2w  = (const float*)d_in[13];
    const float* h2b  = (const float*)d_in[14];
    const float* h3w  = (const float*)d_in[15];
    const float* h3b  = (const float*)d_in[16];
    const float* h4w  = (const float*)d_in[17];
    const float* h4b  = (const float*)d_in[18];
    float* out = (float*)d_out;

    char* ws = (char*)d_ws;
    size_t o = 0;
    float* t2 = (float*)(ws + o); o += (size_t)NB*4*484*4;
    float* t3 = (float*)(ws + o); o += (size_t)NB*200*4;
    float* f1 = (float*)(ws + o); o += (size_t)NB*400*4;
    half_t* g0h = (half_t*)(ws + o); o += (size_t)64*7*512*2;
    half_t* g0l = (half_t*)(ws + o); o += (size_t)64*7*512*2;
    half_t* w1h = (half_t*)(ws + o); o += (size_t)NR*7*9*512*2;
    half_t* w1l = (half_t*)(ws + o); o += (size_t)NR*7*9*512*2;
    half_t* w2h = (half_t*)(ws + o); o += (size_t)NR*5*6*512*2;
    half_t* w2l = (half_t*)(ws + o); o += (size_t)NR*5*6*512*2;
    half_t* w3h = (half_t*)(ws + o); o += (size_t)NR*3*3*512*2;
    half_t* w3l = (half_t*)(ws + o); o += (size_t)NR*3*3*512*2;
    half_t* w4h = (half_t*)(ws + o); o += (size_t)NR*2*1*512*2;
    half_t* w4l = (half_t*)(ws + o); o += (size_t)NR*2*1*512*2;

    conv12_k<<<NB*4, 256, 0, stream>>>(x, c1w, c1b, c2w, c2b, t2);
    conv3_k<<<NB, 256, 0, stream>>>(t2, c3w, c3b, t3);
    fc1_k<<<dim3(7, 8), 256, 0, stream>>>(t3, fc1w, fc1b, f1);
    fc2ws_k<<<32 + 1700, 256, 0, stream>>>(f1, fc2w, fc2b, g0h, g0l,
        h1w, h2w, h3w, h4w, w1h, w1l, w2h, w2l, w3h, w3l, w4h, w4l);
    head_k<<<1664, 256, 0, stream>>>(
        g0h, g0l, w1h, w1l, w2h, w2l, w3h, w3l, w4h, w4l,
        h1b, h2b, h3b, h4b, out);

    (void)in_sizes; (void)n_in; (void)out_size; (void)ws_size;
}